// Round 1
// baseline (264.089 us; speedup 1.0000x reference)
//
#include <hip/hip_runtime.h>
#include <math.h>

#define V 100000
#define D 256
#define B 32
#define N 128
#define K 100
#define NPOS (B * N)
#define NORM_TERM 11.512925f
#define LOG_K 4.605170186f  // log(100)

// softplus(x) = max(x,0) + log1p(exp(-|x|)) — overflow-safe
__device__ __forceinline__ float softplus(float x) {
    return fmaxf(x, 0.f) + log1pf(expf(-fabsf(x)));
}

// One block (4 waves) per (b,n) position. Each wave processes rows
// k = wave, wave+4, ... ; k<K are noise samples, k==K is the target.
// 64 lanes x float4 = one full 1 KB weight row per wave-load, coalesced.
__global__ __launch_bounds__(256) void nce_kernel(
    const int* __restrict__ target,        // (B*N)
    const int* __restrict__ noise,         // (B*N*K)
    const float* __restrict__ hidden,      // (B*N*D)
    const float* __restrict__ weight,      // (V*D)
    const float* __restrict__ bias,        // (V)
    const float* __restrict__ noise_probs, // (V)
    float* __restrict__ out)
{
    const int pos  = blockIdx.x;
    const int tid  = threadIdx.x;
    const int wave = tid >> 6;
    const int lane = tid & 63;

    // lane-private slice of hidden: elements [4*lane, 4*lane+4)
    const float4 h = *reinterpret_cast<const float4*>(
        hidden + (size_t)pos * D + 4 * lane);

    const int* nrow = noise + (size_t)pos * K;

    float loss = 0.f;
    for (int k = wave; k <= K; k += 4) {
        const int idx = (k < K) ? nrow[k] : target[pos];   // wave-uniform
        const float4 w4 = *reinterpret_cast<const float4*>(
            weight + (size_t)idx * D + 4 * lane);
        float s = h.x * w4.x + h.y * w4.y + h.z * w4.z + h.w * w4.w;
        #pragma unroll
        for (int off = 32; off >= 1; off >>= 1)
            s += __shfl_xor(s, off, 64);
        // s now replicated across all 64 lanes
        const float score = s + bias[idx] - NORM_TERM;
        if (k < K) {
            const float logit = score - logf(noise_probs[idx]) - LOG_K;
            loss += softplus(logit);
        } else {
            loss += softplus(-(score - LOG_K));
        }
    }

    // block reduce: loss is replicated within each wave; combine the 4 waves
    __shared__ float wsum[4];
    if (lane == 0) wsum[wave] = loss;
    __syncthreads();
    if (tid == 0) {
        const float block_loss = wsum[0] + wsum[1] + wsum[2] + wsum[3];
        atomicAdd(out, block_loss * (1.0f / (float)NPOS));
    }
}

extern "C" void kernel_launch(void* const* d_in, const int* in_sizes, int n_in,
                              void* d_out, int out_size, void* d_ws, size_t ws_size,
                              hipStream_t stream) {
    const int*   target      = (const int*)d_in[0];
    const int*   noise       = (const int*)d_in[1];
    const float* hidden      = (const float*)d_in[2];
    const float* weight      = (const float*)d_in[3];
    const float* bias        = (const float*)d_in[4];
    const float* noise_probs = (const float*)d_in[5];
    float* out = (float*)d_out;

    // d_out is poisoned 0xAA before every launch — zero it for the atomics
    hipMemsetAsync(out, 0, sizeof(float), stream);

    nce_kernel<<<NPOS, 256, 0, stream>>>(target, noise, hidden, weight,
                                         bias, noise_probs, out);
}

// Round 2
// 237.809 us; speedup vs baseline: 1.1105x; 1.1105x over previous
//
#include <hip/hip_runtime.h>
#include <math.h>

#define V 100000
#define D 256
#define B 32
#define N 128
#define K 100
#define NPOS (B * N)
#define NORM_TERM 11.512925f
#define LOG_K 4.605170186f  // log(100)

// softplus(x) = max(x,0) + log1p(exp(-|x|)) — overflow-safe
__device__ __forceinline__ float softplus(float x) {
    return fmaxf(x, 0.f) + log1pf(expf(-fabsf(x)));
}

// One block (128 threads, 2 waves) per (b,n) position.
// Lane-per-row: thread t (t<=K) computes the full D=256 dot for its own
// gathered weight row (t<K: noise sample t; t==K: target). hidden[pos] is
// wave-uniform -> scalar (s_load) reads; no shuffles in the inner loop;
// epilogue transcendentals run SIMD-parallel across distinct k's.
__global__ __launch_bounds__(128) void nce_kernel(
    const int* __restrict__ target,        // (B*N)
    const int* __restrict__ noise,         // (B*N*K)
    const float* __restrict__ hidden,      // (B*N*D)
    const float* __restrict__ weight,      // (V*D)
    const float* __restrict__ bias,        // (V)
    const float* __restrict__ noise_probs, // (V)
    float* __restrict__ out)
{
    const int pos = blockIdx.x;
    const int tid = threadIdx.x;
    const float* __restrict__ hrow = hidden + (size_t)pos * D;  // wave-uniform

    float loss = 0.f;
    if (tid <= K) {
        const int idx = (tid < K) ? noise[(size_t)pos * K + tid] : target[pos];
        const float* __restrict__ wrow = weight + (size_t)idx * D;

        float ax = 0.f, ay = 0.f, az = 0.f, aw = 0.f;
        // unroll 4: the 4 consecutive float4 loads cover one 64B line per
        // lane per unrolled body -> L1 absorbs the line re-touch.
        #pragma unroll 4
        for (int d = 0; d < D; d += 4) {
            const float4 w4 = *reinterpret_cast<const float4*>(wrow + d);
            ax = fmaf(w4.x, hrow[d + 0], ax);
            ay = fmaf(w4.y, hrow[d + 1], ay);
            az = fmaf(w4.z, hrow[d + 2], az);
            aw = fmaf(w4.w, hrow[d + 3], aw);
        }
        const float dot = (ax + ay) + (az + aw);
        const float score = dot + bias[idx] - NORM_TERM;

        if (tid < K) {
            // noise sample, label 0: softplus(score - log p_noise - log K)
            loss = softplus(score - logf(noise_probs[idx]) - LOG_K);
        } else {
            // target, label 1: softplus(-(score - log K))
            loss = softplus(LOG_K - score);
        }
    }

    // reduce 128 threads: butterfly within each wave, then combine 2 waves
    #pragma unroll
    for (int off = 32; off >= 1; off >>= 1)
        loss += __shfl_xor(loss, off, 64);

    __shared__ float wsum[2];
    if ((tid & 63) == 0) wsum[tid >> 6] = loss;
    __syncthreads();
    if (tid == 0)
        atomicAdd(out, (wsum[0] + wsum[1]) * (1.0f / (float)NPOS));
}

extern "C" void kernel_launch(void* const* d_in, const int* in_sizes, int n_in,
                              void* d_out, int out_size, void* d_ws, size_t ws_size,
                              hipStream_t stream) {
    const int*   target      = (const int*)d_in[0];
    const int*   noise       = (const int*)d_in[1];
    const float* hidden      = (const float*)d_in[2];
    const float* weight      = (const float*)d_in[3];
    const float* bias        = (const float*)d_in[4];
    const float* noise_probs = (const float*)d_in[5];
    float* out = (float*)d_out;

    // d_out is poisoned 0xAA before every launch — zero it for the atomics
    hipMemsetAsync(out, 0, sizeof(float), stream);

    nce_kernel<<<NPOS, 128, 0, stream>>>(target, noise, hidden, weight,
                                         bias, noise_probs, out);
}